// Round 14
// baseline (123.395 us; speedup 1.0000x reference)
//
#include <hip/hip_runtime.h>

#define NF 8
#define BSHIFT 8
#define BNODES 256          // nodes per bucket = 1 << BSHIFT
#define MAXNB 512           // max buckets supported (n_nodes <= 131072)
#define TPB 256
#define TPR 512             // threads for reduce (2 per node)
#define TPBF 512            // threads for fused scatter (4 blocks/CU)
#define CHUNKF 3072         // edges per sort tile (34 KB LDS)
#define KPE 6               // CHUNKF / TPBF records per thread (in registers)
#define NBLKF 1024          // persistent grid for fused scatter
#define CAPB 17408          // per-bucket region capacity (mean 16368 + 8 sigma)
#define SPLIT 8             // slices per bucket (slice ~2048 records)
#define CAP 24              // slots per node per block-slice
#define IDXSTR 26           // padded stride -> conflict-free u16 reads
#define LSLICE 2560         // LDS-resident slice capacity (records)

// P0: transpose q[f][n] -> qT[n][f]; zero govf and the global bucket cursors.
__global__ void k_transpose(const float* __restrict__ q, float* __restrict__ qT,
                            float* __restrict__ govf, unsigned* __restrict__ gcur,
                            int n_nodes, int nb) {
    int n = blockIdx.x * blockDim.x + threadIdx.x;
    if (n < nb) gcur[n] = 0u;
    if (n >= n_nodes) return;
    float4 a, b;
    a.x = q[0 * n_nodes + n]; a.y = q[1 * n_nodes + n];
    a.z = q[2 * n_nodes + n]; a.w = q[3 * n_nodes + n];
    b.x = q[4 * n_nodes + n]; b.y = q[5 * n_nodes + n];
    b.z = q[6 * n_nodes + n]; b.w = q[7 * n_nodes + n];
    float4* dst = reinterpret_cast<float4*>(qT + (size_t)n * NF);
    dst[0] = a; dst[1] = b;
    float* o = govf + (size_t)n * 9;
#pragma unroll
    for (int k = 0; k < 9; ++k) o[k] = 0.f;
}

// P1 (fused, persistent grid, register-held records): per tile
// {pass A: load KPE edges/thread to REGISTERS + position-returning LDS atomic
//  -> global reservation + scan -> place from registers into sorted LDS slots
//  -> run-coalesced write-out}.
__global__ __launch_bounds__(TPBF) void k_scatter_fused(
        const float* __restrict__ edges, const int* __restrict__ senders,
        const int* __restrict__ receivers, int n_edges, int nb, int tiles,
        unsigned* __restrict__ gcur, const float* __restrict__ qT,
        float* __restrict__ govf, uint2* __restrict__ rec) {
    __shared__ uint2 lrec[CHUNKF];            // 24 KB
    __shared__ unsigned short lbkt[CHUNKF];   // 6 KB
    __shared__ unsigned hist[MAXNB];          // 2 KB
    __shared__ unsigned lbase[MAXNB];         // 2 KB
    __shared__ unsigned gbase[MAXNB];         // 2 KB

    for (int t = blockIdx.x; t < tiles; t += gridDim.x) {
        int start = t * CHUNKF;
        int end = min(start + CHUNKF, n_edges);
        int n = end - start;

        for (int i = threadIdx.x; i < nb; i += TPBF) hist[i] = 0u;
        __syncthreads();

        // pass A: stream this thread's KPE edges into registers; ONE LDS atomic
        // per edge returns the tile-local position within its bucket.
        unsigned rcx[KPE], rcy[KPE], meta[KPE];   // meta = (pos<<9) | bkt
#pragma unroll
        for (int k = 0; k < KPE; ++k) {
            int i = (int)threadIdx.x + k * TPBF;
            meta[k] = 0xFFFFFFFFu;
            if (i < n) {
                int e = start + i;
                int s = senders[e];
                int r = receivers[e];
                float ev = edges[e];
                unsigned bkt = (unsigned)r >> BSHIFT;
                unsigned p = atomicAdd(&hist[bkt], 1u);
                rcx[k] = ((unsigned)(r & (BNODES - 1)) << 17) | (unsigned)s;
                rcy[k] = __float_as_uint(ev);
                meta[k] = (p << 9) | bkt;
            }
        }
        __syncthreads();

        // reserve region space per bucket (global atomic, L2-resident counters)
        if (threadIdx.x < (unsigned)nb)
            gbase[threadIdx.x] = atomicAdd(&gcur[threadIdx.x], hist[threadIdx.x]);
        // wave 0: exclusive scan of hist -> lbase (chunks of 64 with carry)
        if (threadIdx.x < 64) {
            int lane = threadIdx.x;
            unsigned carry = 0;
            for (int base = 0; base < nb; base += 64) {
                int bi = base + lane;
                unsigned v = (bi < nb) ? hist[bi] : 0u;
                unsigned x = v;
                for (int d = 1; d < 64; d <<= 1) {
                    unsigned y = __shfl_up(x, d, 64);
                    if (lane >= d) x += y;
                }
                if (bi < nb) lbase[bi] = carry + x - v;
                carry += __shfl(x, 63, 64);
            }
        }
        __syncthreads();

        // phase C: place register-held records at sorted LDS positions
#pragma unroll
        for (int k = 0; k < KPE; ++k) {
            if (meta[k] != 0xFFFFFFFFu) {
                unsigned bkt = meta[k] & 0x1FFu;
                unsigned p   = meta[k] >> 9;
                unsigned slot = lbase[bkt] + p;
                lrec[slot] = make_uint2(rcx[k], rcy[k]);
                lbkt[slot] = (unsigned short)bkt;
            }
        }
        __syncthreads();

        // write-out: consecutive threads -> consecutive addresses per run
        for (int j = threadIdx.x; j < n; j += TPBF) {
            unsigned bkt = lbkt[j];
            uint2 rc = lrec[j];
            unsigned off = gbase[bkt] + ((unsigned)j - lbase[bkt]);
            if (off < CAPB) {
                rec[(size_t)bkt * CAPB + off] = rc;
            } else {
                // region overflow (P ~ 1e-9): exact accumulate via global atomics
                unsigned snd = rc.x & 0x1FFFFu;
                unsigned rl = rc.x >> 17;
                float ev = __uint_as_float(rc.y);
                const float4* qs = reinterpret_cast<const float4*>(qT + (size_t)snd * NF);
                float4 q0 = qs[0];
                float4 q1 = qs[1];
                float* a = govf + ((size_t)bkt * BNODES + rl) * 9;
                atomicAdd(a + 0, q0.x); atomicAdd(a + 1, q0.y);
                atomicAdd(a + 2, q0.z); atomicAdd(a + 3, q0.w);
                atomicAdd(a + 4, q1.x); atomicAdd(a + 5, q1.y);
                atomicAdd(a + 6, q1.z); atomicAdd(a + 7, q1.w);
                atomicAdd(a + 8, ev);
            }
        }
        __syncthreads();
    }
}

// P2: slot-scatter reduce. Slice is DMA-staged into LDS via global_load_lds
// (no VGPR round-trip, no dependent chain), then pass 1 runs atomics off LDS.
__global__ __launch_bounds__(TPR) void k_reduce_slot(
        const uint2* __restrict__ rec, const unsigned* __restrict__ gcur,
        const float* __restrict__ qT, float* __restrict__ part,
        float* __restrict__ govf, int n_nodes) {
    __shared__ __align__(16) uint2 lrec[LSLICE];     // 20 KB (reused as scratch)
    __shared__ unsigned short idx[BNODES * IDXSTR];  // 13.3 KB
    __shared__ unsigned cur[BNODES];                 // 1 KB
    int t = threadIdx.x;
    if (t < BNODES) cur[t] = 0;

    int bkt = blockIdx.x / SPLIT;
    int s   = blockIdx.x % SPLIT;
    unsigned len = gcur[bkt];
    if (len > CAPB) len = CAPB;
    size_t base = (size_t)bkt * CAPB;
    unsigned a0 = ((unsigned)(((unsigned long long)len * s) / SPLIT)) & ~1u;
    unsigned a1 = (s + 1 == SPLIT) ? len
                : ((unsigned)(((unsigned long long)len * (s + 1)) / SPLIT)) & ~1u;
    unsigned slice = a1 - a0;
    unsigned staged = slice < LSLICE ? slice : LSLICE;

    // async DMA: stage `staged` records (16B per lane per call) into lrec.
    // (base + a0) is even -> byte address 16B-aligned. Overstage tail reads
    // stay inside the workspace (rec is followed by other ws buffers).
    {
        int wid = t >> 6, lane = t & 63;
        unsigned ncalls = (staged * 8u + 1023u) >> 10;   // 1 KB per call
        const char* g0 = (const char*)(rec + base + a0);
        for (unsigned c = wid; c < ncalls; c += TPR / 64) {
            const char* g = g0 + (size_t)c * 1024 + (size_t)lane * 16;
            char* l = (char*)lrec + (size_t)c * 1024;   // wave-uniform base
            __builtin_amdgcn_global_load_lds(
                (const __attribute__((address_space(1))) void*)g,
                (__attribute__((address_space(3))) void*)l, 16, 0, 0);
        }
    }
    __syncthreads();   // drains vmcnt (barrier implies full waitcnt)

    // pass 1: slot-scatter indices off LDS (1 LDS atomic/edge)
    for (unsigned i = t; i < staged; i += TPR) {
        uint2 rc = lrec[i];
        unsigned rl = rc.x >> 17;
        unsigned pos = atomicAdd(&cur[rl], 1u);
        if (pos < CAP) {
            idx[rl * IDXSTR + pos] = (unsigned short)i;
        } else {
            unsigned snd = rc.x & 0x1FFFFu;
            float ev = __uint_as_float(rc.y);
            const float4* qs = reinterpret_cast<const float4*>(qT + (size_t)snd * NF);
            float4 q0 = qs[0];
            float4 q1 = qs[1];
            float* a = govf + ((size_t)bkt * BNODES + rl) * 9;
            atomicAdd(a + 0, q0.x); atomicAdd(a + 1, q0.y);
            atomicAdd(a + 2, q0.z); atomicAdd(a + 3, q0.w);
            atomicAdd(a + 4, q1.x); atomicAdd(a + 5, q1.y);
            atomicAdd(a + 6, q1.z); atomicAdd(a + 7, q1.w);
            atomicAdd(a + 8, ev);
        }
    }
    // slice tail beyond LSLICE (rare): direct global reads, same slot lists
    for (unsigned i = LSLICE + t; i < slice; i += TPR) {
        uint2 rc = rec[base + a0 + i];
        unsigned rl = rc.x >> 17;
        unsigned pos = atomicAdd(&cur[rl], 1u);
        if (pos < CAP) {
            idx[rl * IDXSTR + pos] = (unsigned short)i;
        } else {
            unsigned snd = rc.x & 0x1FFFFu;
            float ev = __uint_as_float(rc.y);
            const float4* qs = reinterpret_cast<const float4*>(qT + (size_t)snd * NF);
            float4 q0 = qs[0];
            float4 q1 = qs[1];
            float* a = govf + ((size_t)bkt * BNODES + rl) * 9;
            atomicAdd(a + 0, q0.x); atomicAdd(a + 1, q0.y);
            atomicAdd(a + 2, q0.z); atomicAdd(a + 3, q0.w);
            atomicAdd(a + 4, q1.x); atomicAdd(a + 5, q1.y);
            atomicAdd(a + 6, q1.z); atomicAdd(a + 7, q1.w);
            atomicAdd(a + 8, ev);
        }
    }
    __syncthreads();

    // pass 2: threads (2n, 2n+1) own node n; parity-split slot list.
    int node = t >> 1;
    int parity = t & 1;
    float m[9];
#pragma unroll
    for (int k = 0; k < 9; ++k) m[k] = 0.f;
    unsigned cntv = cur[node];
    if (cntv > CAP) cntv = CAP;
    for (unsigned j = parity; j < cntv; j += 2) {
        unsigned i0 = idx[node * IDXSTR + j];
        uint2 rc0 = (i0 < LSLICE) ? lrec[i0] : rec[base + a0 + i0];
        const float4* qs0 = reinterpret_cast<const float4*>(qT + (size_t)(rc0.x & 0x1FFFFu) * NF);
        float4 a0v = qs0[0], a1v = qs0[1];
        m[0] += a0v.x; m[1] += a0v.y; m[2] += a0v.z; m[3] += a0v.w;
        m[4] += a1v.x; m[5] += a1v.y; m[6] += a1v.z; m[7] += a1v.w;
        m[8] += __uint_as_float(rc0.y);
    }
    __syncthreads();   // all lrec reads done; safe to reuse as scratch

    float* scratch = reinterpret_cast<float*>(lrec);  // 256*9 floats = 9 KB
    if (parity == 1) {
        float* d = scratch + (size_t)node * 9;
#pragma unroll
        for (int k = 0; k < 9; ++k) d[k] = m[k];
    }
    __syncthreads();
    if (parity == 0) {
        const float* p2 = scratch + (size_t)node * 9;
        float* dst = part + (size_t)blockIdx.x * (BNODES * 9) + (size_t)node * 9;
#pragma unroll
        for (int k = 0; k < 9; ++k) dst[k] = m[k] + p2[k];
    }
}

// P3: sum SPLIT partials per node (+ global overflow), fused finalize.
__global__ void k_finalize2(const float* __restrict__ part, const float* __restrict__ govf,
                            const float* __restrict__ q,
                            const float* __restrict__ dtp, const float* __restrict__ w_self,
                            const float* __restrict__ w_msg, const float* __restrict__ w_edge,
                            const float* __restrict__ bv, float* __restrict__ out,
                            int split, int n_nodes) {
    int n = blockIdx.x * blockDim.x + threadIdx.x;
    if (n >= n_nodes) return;
    int bkt = n >> BSHIFT;
    int rl = n & (BNODES - 1);
    float m[9];
#pragma unroll
    for (int f = 0; f < 9; ++f) m[f] = govf[(size_t)n * 9 + f];
    for (int s = 0; s < split; ++s) {
        const float* p = part + ((size_t)(bkt * split + s) * BNODES + rl) * 9;
#pragma unroll
        for (int f = 0; f < 9; ++f) m[f] += p[f];
    }
    float dtv = dtp[0];
    float evs = m[8];
#pragma unroll
    for (int f = 0; f < NF; ++f) {
        float msg = m[f] + w_edge[f] * evs;
        out[(size_t)f * n_nodes + n] =
            dtv * (w_self[f] * q[(size_t)f * n_nodes + n] + w_msg[f] * msg + bv[f]);
    }
}

// ---------- last-resort fallback (global atomics) ----------
__global__ void k_transpose_zero(const float* __restrict__ q, float* __restrict__ qT,
                                 float* __restrict__ msgT, int n_nodes) {
    int n = blockIdx.x * blockDim.x + threadIdx.x;
    if (n >= n_nodes) return;
    float v[NF];
#pragma unroll
    for (int f = 0; f < NF; ++f) v[f] = q[f * n_nodes + n];
    float4* dst = reinterpret_cast<float4*>(qT + (size_t)n * NF);
    dst[0] = make_float4(v[0], v[1], v[2], v[3]);
    dst[1] = make_float4(v[4], v[5], v[6], v[7]);
    float4 z = make_float4(0.f, 0.f, 0.f, 0.f);
    float4* m = reinterpret_cast<float4*>(msgT + (size_t)n * NF);
    m[0] = z; m[1] = z;
}

__global__ void k_edge_scatter(const float* __restrict__ edges, const int* __restrict__ senders,
                               const int* __restrict__ receivers, const float* __restrict__ qT,
                               float* __restrict__ msgT, const float* __restrict__ w_edge,
                               int n_edges) {
    float we[NF];
#pragma unroll
    for (int f = 0; f < NF; ++f) we[f] = w_edge[f];
    int idx = blockIdx.x * blockDim.x + threadIdx.x;
    int stride = gridDim.x * blockDim.x;
    for (int e = idx; e < n_edges; e += stride) {
        int s = senders[e];
        int r = receivers[e];
        float ev = edges[e];
        const float4* qs = reinterpret_cast<const float4*>(qT + (size_t)s * NF);
        float4 q0 = qs[0];
        float4 q1 = qs[1];
        float* m = msgT + (size_t)r * NF;
        atomicAdd(m + 0, q0.x + we[0] * ev);
        atomicAdd(m + 1, q0.y + we[1] * ev);
        atomicAdd(m + 2, q0.z + we[2] * ev);
        atomicAdd(m + 3, q0.w + we[3] * ev);
        atomicAdd(m + 4, q1.x + we[4] * ev);
        atomicAdd(m + 5, q1.y + we[5] * ev);
        atomicAdd(m + 6, q1.z + we[6] * ev);
        atomicAdd(m + 7, q1.w + we[7] * ev);
    }
}

__global__ void k_finalize(const float* __restrict__ q, const float* __restrict__ msgT,
                           const float* __restrict__ dt, const float* __restrict__ w_self,
                           const float* __restrict__ w_msg, const float* __restrict__ b,
                           float* __restrict__ out, int n_nodes) {
    int n = blockIdx.x * blockDim.x + threadIdx.x;
    if (n >= n_nodes) return;
    float dtv = dt[0];
    const float4* m4 = reinterpret_cast<const float4*>(msgT + (size_t)n * NF);
    float4 m0 = m4[0];
    float4 m1 = m4[1];
    float mv[NF] = {m0.x, m0.y, m0.z, m0.w, m1.x, m1.y, m1.z, m1.w};
#pragma unroll
    for (int f = 0; f < NF; ++f) {
        out[f * n_nodes + n] = dtv * (w_self[f] * q[f * n_nodes + n] + w_msg[f] * mv[f] + b[f]);
    }
}

// ---------------- launch ----------------
extern "C" void kernel_launch(void* const* d_in, const int* in_sizes, int n_in,
                              void* d_out, int out_size, void* d_ws, size_t ws_size,
                              hipStream_t stream) {
    const float* q         = (const float*)d_in[0];
    const float* edges     = (const float*)d_in[1];
    const int*   senders   = (const int*)d_in[2];
    const int*   receivers = (const int*)d_in[3];
    const float* dt        = (const float*)d_in[4];
    const float* w_self    = (const float*)d_in[5];
    const float* w_msg     = (const float*)d_in[6];
    const float* w_edge    = (const float*)d_in[7];
    const float* b         = (const float*)d_in[8];
    float* out = (float*)d_out;

    const int n_nodes = in_sizes[0] / NF;   // 100000
    const int n_edges = in_sizes[2];        // 6400000
    const int nb = (n_nodes + BNODES - 1) >> BSHIFT;
    const int tiles = (n_edges + CHUNKF - 1) / CHUNKF;

    size_t rec_bytes  = (size_t)nb * CAPB * 8;
    size_t qT_bytes   = (size_t)n_nodes * NF * 4;
    size_t gcur_bytes = 256 + (size_t)nb * 4;           // padded
    size_t govf_bytes = (size_t)nb * BNODES * 9 * 4;
    size_t part_bytes = (size_t)SPLIT * nb * BNODES * 9 * 4;
    size_t need = rec_bytes + qT_bytes + gcur_bytes + govf_bytes + part_bytes + 4096;

    // mean bucket load must be comfortably under CAPB (8+ sigma margin)
    double mean_per_bucket = (double)n_edges / (double)nb;
    bool ok = (n_nodes <= 131072) && (nb <= MAXNB) && (need <= ws_size) &&
              (mean_per_bucket + 8.0 * __builtin_sqrt(mean_per_bucket) < (double)CAPB);

    if (ok) {
        char* p = (char*)d_ws;
        uint2*    rec  = (uint2*)p;    p += rec_bytes;
        float*    qT   = (float*)p;    p += qT_bytes;
        unsigned* gcur = (unsigned*)p; p += gcur_bytes;
        float*    govf = (float*)p;    p += govf_bytes;
        float*    part = (float*)(((uintptr_t)p + 255) & ~(uintptr_t)255);

        int nblk_f = tiles < NBLKF ? tiles : NBLKF;

        k_transpose<<<(n_nodes + TPB - 1) / TPB, TPB, 0, stream>>>(q, qT, govf, gcur,
                                                                   n_nodes, nb);
        k_scatter_fused<<<nblk_f, TPBF, 0, stream>>>(edges, senders, receivers, n_edges,
                                                     nb, tiles, gcur, qT, govf, rec);
        k_reduce_slot<<<nb * SPLIT, TPR, 0, stream>>>(rec, gcur, qT, part, govf, n_nodes);
        k_finalize2<<<(n_nodes + TPB - 1) / TPB, TPB, 0, stream>>>(
            part, govf, q, dt, w_self, w_msg, w_edge, b, out, SPLIT, n_nodes);
    } else {
        float* qT   = (float*)d_ws;
        float* msgT = qT + (size_t)n_nodes * NF;
        k_transpose_zero<<<(n_nodes + TPB - 1) / TPB, TPB, 0, stream>>>(q, qT, msgT, n_nodes);
        k_edge_scatter<<<3072, TPB, 0, stream>>>(edges, senders, receivers, qT, msgT,
                                                 w_edge, n_edges);
        k_finalize<<<(n_nodes + TPB - 1) / TPB, TPB, 0, stream>>>(q, msgT, dt, w_self, w_msg,
                                                                  b, out, n_nodes);
    }
}

// Round 15
// 107.173 us; speedup vs baseline: 1.1514x; 1.1514x over previous
//
#include <hip/hip_runtime.h>

#define NF 8
#define BSHIFT 8
#define BNODES 256          // nodes per bucket = 1 << BSHIFT
#define MAXNB 512           // max buckets supported (n_nodes <= 131072)
#define TPB 256
#define TPR 512             // threads for reduce (2 per node)
#define TPBF 1024           // threads for fused scatter (R13 best)
#define CHUNKF 6144         // edges per sort tile (66 KB LDS -> 2 blocks/CU)
#define KPE 6               // CHUNKF / TPBF records per thread (in registers)
#define NBLKF 512           // persistent grid for fused scatter
#define CAPB 17408          // per-bucket region capacity (mean 16368 + 8 sigma)
#define SPLIT 8             // slices per bucket (slice ~2048 records)
#define CAP 24              // slots per node per block-slice
#define IDXSTR 26           // padded stride -> conflict-free u16 reads
#define LSLICE 2560         // LDS-resident slice capacity (records)

// P0: transpose q[f][n] -> qT[n][f]; zero govf and the global bucket cursors.
__global__ void k_transpose(const float* __restrict__ q, float* __restrict__ qT,
                            float* __restrict__ govf, unsigned* __restrict__ gcur,
                            int n_nodes, int nb) {
    int n = blockIdx.x * blockDim.x + threadIdx.x;
    if (n < nb) gcur[n] = 0u;
    if (n >= n_nodes) return;
    float4 a, b;
    a.x = q[0 * n_nodes + n]; a.y = q[1 * n_nodes + n];
    a.z = q[2 * n_nodes + n]; a.w = q[3 * n_nodes + n];
    b.x = q[4 * n_nodes + n]; b.y = q[5 * n_nodes + n];
    b.z = q[6 * n_nodes + n]; b.w = q[7 * n_nodes + n];
    float4* dst = reinterpret_cast<float4*>(qT + (size_t)n * NF);
    dst[0] = a; dst[1] = b;
    float* o = govf + (size_t)n * 9;
#pragma unroll
    for (int k = 0; k < 9; ++k) o[k] = 0.f;
}

// P1 (fused, persistent grid, register-held records — R13 config): per tile
// {pass A: load KPE edges/thread to REGISTERS + position-returning LDS atomic
//  -> global reservation + scan -> place from registers into sorted LDS slots
//  -> run-coalesced write-out}.
__global__ __launch_bounds__(TPBF) void k_scatter_fused(
        const float* __restrict__ edges, const int* __restrict__ senders,
        const int* __restrict__ receivers, int n_edges, int nb, int tiles,
        unsigned* __restrict__ gcur, const float* __restrict__ qT,
        float* __restrict__ govf, uint2* __restrict__ rec) {
    __shared__ uint2 lrec[CHUNKF];            // 48 KB
    __shared__ unsigned short lbkt[CHUNKF];   // 12 KB
    __shared__ unsigned hist[MAXNB];          // 2 KB
    __shared__ unsigned lbase[MAXNB];         // 2 KB
    __shared__ unsigned gbase[MAXNB];         // 2 KB

    for (int t = blockIdx.x; t < tiles; t += gridDim.x) {
        int start = t * CHUNKF;
        int end = min(start + CHUNKF, n_edges);
        int n = end - start;

        for (int i = threadIdx.x; i < nb; i += TPBF) hist[i] = 0u;
        __syncthreads();

        // pass A: stream this thread's KPE edges into registers; ONE LDS atomic
        // per edge returns the tile-local position within its bucket.
        unsigned rcx[KPE], rcy[KPE], meta[KPE];   // meta = (pos<<9) | bkt
#pragma unroll
        for (int k = 0; k < KPE; ++k) {
            int i = (int)threadIdx.x + k * TPBF;
            meta[k] = 0xFFFFFFFFu;
            if (i < n) {
                int e = start + i;
                int s = senders[e];
                int r = receivers[e];
                float ev = edges[e];
                unsigned bkt = (unsigned)r >> BSHIFT;
                unsigned p = atomicAdd(&hist[bkt], 1u);
                rcx[k] = ((unsigned)(r & (BNODES - 1)) << 17) | (unsigned)s;
                rcy[k] = __float_as_uint(ev);
                meta[k] = (p << 9) | bkt;
            }
        }
        __syncthreads();

        // reserve region space per bucket (global atomic, L2-resident counters)
        if (threadIdx.x < (unsigned)nb)
            gbase[threadIdx.x] = atomicAdd(&gcur[threadIdx.x], hist[threadIdx.x]);
        // wave 0: exclusive scan of hist -> lbase (chunks of 64 with carry)
        if (threadIdx.x < 64) {
            int lane = threadIdx.x;
            unsigned carry = 0;
            for (int base = 0; base < nb; base += 64) {
                int bi = base + lane;
                unsigned v = (bi < nb) ? hist[bi] : 0u;
                unsigned x = v;
                for (int d = 1; d < 64; d <<= 1) {
                    unsigned y = __shfl_up(x, d, 64);
                    if (lane >= d) x += y;
                }
                if (bi < nb) lbase[bi] = carry + x - v;
                carry += __shfl(x, 63, 64);
            }
        }
        __syncthreads();

        // phase C: place register-held records at sorted LDS positions
#pragma unroll
        for (int k = 0; k < KPE; ++k) {
            if (meta[k] != 0xFFFFFFFFu) {
                unsigned bkt = meta[k] & 0x1FFu;
                unsigned p   = meta[k] >> 9;
                unsigned slot = lbase[bkt] + p;
                lrec[slot] = make_uint2(rcx[k], rcy[k]);
                lbkt[slot] = (unsigned short)bkt;
            }
        }
        __syncthreads();

        // write-out: consecutive threads -> consecutive addresses per run
        for (int j = threadIdx.x; j < n; j += TPBF) {
            unsigned bkt = lbkt[j];
            uint2 rc = lrec[j];
            unsigned off = gbase[bkt] + ((unsigned)j - lbase[bkt]);
            if (off < CAPB) {
                rec[(size_t)bkt * CAPB + off] = rc;
            } else {
                // region overflow (P ~ 1e-9): exact accumulate via global atomics
                unsigned snd = rc.x & 0x1FFFFu;
                unsigned rl = rc.x >> 17;
                float ev = __uint_as_float(rc.y);
                const float4* qs = reinterpret_cast<const float4*>(qT + (size_t)snd * NF);
                float4 q0 = qs[0];
                float4 q1 = qs[1];
                float* a = govf + ((size_t)bkt * BNODES + rl) * 9;
                atomicAdd(a + 0, q0.x); atomicAdd(a + 1, q0.y);
                atomicAdd(a + 2, q0.z); atomicAdd(a + 3, q0.w);
                atomicAdd(a + 4, q1.x); atomicAdd(a + 5, q1.y);
                atomicAdd(a + 6, q1.z); atomicAdd(a + 7, q1.w);
                atomicAdd(a + 8, ev);
            }
        }
        __syncthreads();
    }
}

// P2: slot-scatter reduce (R8/R13 structure) with paired uint4 streaming in
// pass 1: 2 records per 16B load (optimal coalescing, half the load/LDS-write
// instruction count). Slice start forced even for alignment.
__global__ __launch_bounds__(TPR) void k_reduce_slot(
        const uint2* __restrict__ rec, const unsigned* __restrict__ gcur,
        const float* __restrict__ qT, float* __restrict__ part,
        float* __restrict__ govf, int n_nodes) {
    __shared__ __align__(16) uint2 lrec[LSLICE];     // 20 KB (reused as scratch)
    __shared__ unsigned short idx[BNODES * IDXSTR];  // 13.3 KB
    __shared__ unsigned cur[BNODES];                 // 1 KB
    int t = threadIdx.x;
    if (t < BNODES) cur[t] = 0;
    __syncthreads();

    int bkt = blockIdx.x / SPLIT;
    int s   = blockIdx.x % SPLIT;
    unsigned len = gcur[bkt];
    if (len > CAPB) len = CAPB;
    size_t base = (size_t)bkt * CAPB;
    unsigned a0 = ((unsigned)(((unsigned long long)len * s) / SPLIT)) & ~1u;
    unsigned a1 = (s + 1 == SPLIT) ? len
                : ((unsigned)(((unsigned long long)len * (s + 1)) / SPLIT)) & ~1u;
    unsigned slice = a1 - a0;
    unsigned staged = slice < LSLICE ? slice : LSLICE;

    // pass 1: stream 2 records per thread-iteration (uint4), stage into LDS,
    // slot-scatter indices (1 LDS atomic per record).
    for (unsigned i = 2u * t; i < staged; i += 2u * TPR) {
        uint4 two = *reinterpret_cast<const uint4*>(rec + base + a0 + i);
        *reinterpret_cast<uint4*>(lrec + i) = two;   // stages records i, i+1
        {
            unsigned rl = two.x >> 17;
            unsigned pos = atomicAdd(&cur[rl], 1u);
            if (pos < CAP) {
                idx[rl * IDXSTR + pos] = (unsigned short)i;
            } else {
                unsigned snd = two.x & 0x1FFFFu;
                float ev = __uint_as_float(two.y);
                const float4* qs = reinterpret_cast<const float4*>(qT + (size_t)snd * NF);
                float4 q0 = qs[0];
                float4 q1 = qs[1];
                float* a = govf + ((size_t)bkt * BNODES + rl) * 9;
                atomicAdd(a + 0, q0.x); atomicAdd(a + 1, q0.y);
                atomicAdd(a + 2, q0.z); atomicAdd(a + 3, q0.w);
                atomicAdd(a + 4, q1.x); atomicAdd(a + 5, q1.y);
                atomicAdd(a + 6, q1.z); atomicAdd(a + 7, q1.w);
                atomicAdd(a + 8, ev);
            }
        }
        if (i + 1 < staged) {
            unsigned rl = two.z >> 17;
            unsigned pos = atomicAdd(&cur[rl], 1u);
            if (pos < CAP) {
                idx[rl * IDXSTR + pos] = (unsigned short)(i + 1);
            } else {
                unsigned snd = two.z & 0x1FFFFu;
                float ev = __uint_as_float(two.w);
                const float4* qs = reinterpret_cast<const float4*>(qT + (size_t)snd * NF);
                float4 q0 = qs[0];
                float4 q1 = qs[1];
                float* a = govf + ((size_t)bkt * BNODES + rl) * 9;
                atomicAdd(a + 0, q0.x); atomicAdd(a + 1, q0.y);
                atomicAdd(a + 2, q0.z); atomicAdd(a + 3, q0.w);
                atomicAdd(a + 4, q1.x); atomicAdd(a + 5, q1.y);
                atomicAdd(a + 6, q1.z); atomicAdd(a + 7, q1.w);
                atomicAdd(a + 8, ev);
            }
        }
    }
    // slice tail beyond LSLICE (rare): direct global reads, same slot lists
    for (unsigned i = LSLICE + t; i < slice; i += TPR) {
        uint2 rc = rec[base + a0 + i];
        unsigned rl = rc.x >> 17;
        unsigned pos = atomicAdd(&cur[rl], 1u);
        if (pos < CAP) {
            idx[rl * IDXSTR + pos] = (unsigned short)i;
        } else {
            unsigned snd = rc.x & 0x1FFFFu;
            float ev = __uint_as_float(rc.y);
            const float4* qs = reinterpret_cast<const float4*>(qT + (size_t)snd * NF);
            float4 q0 = qs[0];
            float4 q1 = qs[1];
            float* a = govf + ((size_t)bkt * BNODES + rl) * 9;
            atomicAdd(a + 0, q0.x); atomicAdd(a + 1, q0.y);
            atomicAdd(a + 2, q0.z); atomicAdd(a + 3, q0.w);
            atomicAdd(a + 4, q1.x); atomicAdd(a + 5, q1.y);
            atomicAdd(a + 6, q1.z); atomicAdd(a + 7, q1.w);
            atomicAdd(a + 8, ev);
        }
    }
    __syncthreads();

    // pass 2: threads (2n, 2n+1) own node n; parity-split slot list.
    int node = t >> 1;
    int parity = t & 1;
    float m[9];
#pragma unroll
    for (int k = 0; k < 9; ++k) m[k] = 0.f;
    unsigned cntv = cur[node];
    if (cntv > CAP) cntv = CAP;
    for (unsigned j = parity; j < cntv; j += 2) {
        unsigned i0 = idx[node * IDXSTR + j];
        uint2 rc0 = (i0 < LSLICE) ? lrec[i0] : rec[base + a0 + i0];
        const float4* qs0 = reinterpret_cast<const float4*>(qT + (size_t)(rc0.x & 0x1FFFFu) * NF);
        float4 a0v = qs0[0], a1v = qs0[1];
        m[0] += a0v.x; m[1] += a0v.y; m[2] += a0v.z; m[3] += a0v.w;
        m[4] += a1v.x; m[5] += a1v.y; m[6] += a1v.z; m[7] += a1v.w;
        m[8] += __uint_as_float(rc0.y);
    }
    __syncthreads();   // all lrec reads done; safe to reuse as scratch

    float* scratch = reinterpret_cast<float*>(lrec);  // 256*9 floats = 9 KB
    if (parity == 1) {
        float* d = scratch + (size_t)node * 9;
#pragma unroll
        for (int k = 0; k < 9; ++k) d[k] = m[k];
    }
    __syncthreads();
    if (parity == 0) {
        const float* p2 = scratch + (size_t)node * 9;
        float* dst = part + (size_t)blockIdx.x * (BNODES * 9) + (size_t)node * 9;
#pragma unroll
        for (int k = 0; k < 9; ++k) dst[k] = m[k] + p2[k];
    }
}

// P3: sum SPLIT partials per node (+ global overflow), fused finalize.
__global__ void k_finalize2(const float* __restrict__ part, const float* __restrict__ govf,
                            const float* __restrict__ q,
                            const float* __restrict__ dtp, const float* __restrict__ w_self,
                            const float* __restrict__ w_msg, const float* __restrict__ w_edge,
                            const float* __restrict__ bv, float* __restrict__ out,
                            int split, int n_nodes) {
    int n = blockIdx.x * blockDim.x + threadIdx.x;
    if (n >= n_nodes) return;
    int bkt = n >> BSHIFT;
    int rl = n & (BNODES - 1);
    float m[9];
#pragma unroll
    for (int f = 0; f < 9; ++f) m[f] = govf[(size_t)n * 9 + f];
    for (int s = 0; s < split; ++s) {
        const float* p = part + ((size_t)(bkt * split + s) * BNODES + rl) * 9;
#pragma unroll
        for (int f = 0; f < 9; ++f) m[f] += p[f];
    }
    float dtv = dtp[0];
    float evs = m[8];
#pragma unroll
    for (int f = 0; f < NF; ++f) {
        float msg = m[f] + w_edge[f] * evs;
        out[(size_t)f * n_nodes + n] =
            dtv * (w_self[f] * q[(size_t)f * n_nodes + n] + w_msg[f] * msg + bv[f]);
    }
}

// ---------- last-resort fallback (global atomics) ----------
__global__ void k_transpose_zero(const float* __restrict__ q, float* __restrict__ qT,
                                 float* __restrict__ msgT, int n_nodes) {
    int n = blockIdx.x * blockDim.x + threadIdx.x;
    if (n >= n_nodes) return;
    float v[NF];
#pragma unroll
    for (int f = 0; f < NF; ++f) v[f] = q[f * n_nodes + n];
    float4* dst = reinterpret_cast<float4*>(qT + (size_t)n * NF);
    dst[0] = make_float4(v[0], v[1], v[2], v[3]);
    dst[1] = make_float4(v[4], v[5], v[6], v[7]);
    float4 z = make_float4(0.f, 0.f, 0.f, 0.f);
    float4* m = reinterpret_cast<float4*>(msgT + (size_t)n * NF);
    m[0] = z; m[1] = z;
}

__global__ void k_edge_scatter(const float* __restrict__ edges, const int* __restrict__ senders,
                               const int* __restrict__ receivers, const float* __restrict__ qT,
                               float* __restrict__ msgT, const float* __restrict__ w_edge,
                               int n_edges) {
    float we[NF];
#pragma unroll
    for (int f = 0; f < NF; ++f) we[f] = w_edge[f];
    int idx = blockIdx.x * blockDim.x + threadIdx.x;
    int stride = gridDim.x * blockDim.x;
    for (int e = idx; e < n_edges; e += stride) {
        int s = senders[e];
        int r = receivers[e];
        float ev = edges[e];
        const float4* qs = reinterpret_cast<const float4*>(qT + (size_t)s * NF);
        float4 q0 = qs[0];
        float4 q1 = qs[1];
        float* m = msgT + (size_t)r * NF;
        atomicAdd(m + 0, q0.x + we[0] * ev);
        atomicAdd(m + 1, q0.y + we[1] * ev);
        atomicAdd(m + 2, q0.z + we[2] * ev);
        atomicAdd(m + 3, q0.w + we[3] * ev);
        atomicAdd(m + 4, q1.x + we[4] * ev);
        atomicAdd(m + 5, q1.y + we[5] * ev);
        atomicAdd(m + 6, q1.z + we[6] * ev);
        atomicAdd(m + 7, q1.w + we[7] * ev);
    }
}

__global__ void k_finalize(const float* __restrict__ q, const float* __restrict__ msgT,
                           const float* __restrict__ dt, const float* __restrict__ w_self,
                           const float* __restrict__ w_msg, const float* __restrict__ b,
                           float* __restrict__ out, int n_nodes) {
    int n = blockIdx.x * blockDim.x + threadIdx.x;
    if (n >= n_nodes) return;
    float dtv = dt[0];
    const float4* m4 = reinterpret_cast<const float4*>(msgT + (size_t)n * NF);
    float4 m0 = m4[0];
    float4 m1 = m4[1];
    float mv[NF] = {m0.x, m0.y, m0.z, m0.w, m1.x, m1.y, m1.z, m1.w};
#pragma unroll
    for (int f = 0; f < NF; ++f) {
        out[f * n_nodes + n] = dtv * (w_self[f] * q[f * n_nodes + n] + w_msg[f] * mv[f] + b[f]);
    }
}

// ---------------- launch ----------------
extern "C" void kernel_launch(void* const* d_in, const int* in_sizes, int n_in,
                              void* d_out, int out_size, void* d_ws, size_t ws_size,
                              hipStream_t stream) {
    const float* q         = (const float*)d_in[0];
    const float* edges     = (const float*)d_in[1];
    const int*   senders   = (const int*)d_in[2];
    const int*   receivers = (const int*)d_in[3];
    const float* dt        = (const float*)d_in[4];
    const float* w_self    = (const float*)d_in[5];
    const float* w_msg     = (const float*)d_in[6];
    const float* w_edge    = (const float*)d_in[7];
    const float* b         = (const float*)d_in[8];
    float* out = (float*)d_out;

    const int n_nodes = in_sizes[0] / NF;   // 100000
    const int n_edges = in_sizes[2];        // 6400000
    const int nb = (n_nodes + BNODES - 1) >> BSHIFT;
    const int tiles = (n_edges + CHUNKF - 1) / CHUNKF;

    size_t rec_bytes  = (size_t)nb * CAPB * 8;
    size_t qT_bytes   = (size_t)n_nodes * NF * 4;
    size_t gcur_bytes = 256 + (size_t)nb * 4;           // padded
    size_t govf_bytes = (size_t)nb * BNODES * 9 * 4;
    size_t part_bytes = (size_t)SPLIT * nb * BNODES * 9 * 4;
    size_t need = rec_bytes + qT_bytes + gcur_bytes + govf_bytes + part_bytes + 4096;

    // mean bucket load must be comfortably under CAPB (8+ sigma margin)
    double mean_per_bucket = (double)n_edges / (double)nb;
    bool ok = (n_nodes <= 131072) && (nb <= MAXNB) && (need <= ws_size) &&
              (mean_per_bucket + 8.0 * __builtin_sqrt(mean_per_bucket) < (double)CAPB);

    if (ok) {
        char* p = (char*)d_ws;
        uint2*    rec  = (uint2*)p;    p += rec_bytes;
        float*    qT   = (float*)p;    p += qT_bytes;
        unsigned* gcur = (unsigned*)p; p += gcur_bytes;
        float*    govf = (float*)p;    p += govf_bytes;
        float*    part = (float*)(((uintptr_t)p + 255) & ~(uintptr_t)255);

        int nblk_f = tiles < NBLKF ? tiles : NBLKF;

        k_transpose<<<(n_nodes + TPB - 1) / TPB, TPB, 0, stream>>>(q, qT, govf, gcur,
                                                                   n_nodes, nb);
        k_scatter_fused<<<nblk_f, TPBF, 0, stream>>>(edges, senders, receivers, n_edges,
                                                     nb, tiles, gcur, qT, govf, rec);
        k_reduce_slot<<<nb * SPLIT, TPR, 0, stream>>>(rec, gcur, qT, part, govf, n_nodes);
        k_finalize2<<<(n_nodes + TPB - 1) / TPB, TPB, 0, stream>>>(
            part, govf, q, dt, w_self, w_msg, w_edge, b, out, SPLIT, n_nodes);
    } else {
        float* qT   = (float*)d_ws;
        float* msgT = qT + (size_t)n_nodes * NF;
        k_transpose_zero<<<(n_nodes + TPB - 1) / TPB, TPB, 0, stream>>>(q, qT, msgT, n_nodes);
        k_edge_scatter<<<3072, TPB, 0, stream>>>(edges, senders, receivers, qT, msgT,
                                                 w_edge, n_edges);
        k_finalize<<<(n_nodes + TPB - 1) / TPB, TPB, 0, stream>>>(q, msgT, dt, w_self, w_msg,
                                                                  b, out, n_nodes);
    }
}